// Round 15
// baseline (249.713 us; speedup 1.0000x reference)
//
#include <hip/hip_runtime.h>
#include <hip/hip_bf16.h>
#include <stdint.h>

typedef __bf16 bf16;
typedef __attribute__((ext_vector_type(8))) __bf16 bf16x8;
typedef __attribute__((ext_vector_type(4))) float f32x4;

#define DEVI __device__ __forceinline__

constexpr int Bz = 4, Sz = 2048, Dz = 512, Hz = 8, DKz = 64, DFFz = 2048;
constexpr int ROWSz = Bz * Sz;  // 8192
constexpr float EPSf = 1e-5f;
constexpr float C2f = 0.125f * 1.44269504088896f;  // 1/sqrt(DK) * log2(e)

// ---- async global->LDS, 16B per lane. LDS dest is wave-uniform base + lane*16.
DEVI void load_lds16(void* lds, const void* g) {
  __builtin_amdgcn_global_load_lds(
      (const __attribute__((address_space(1))) void*)(uintptr_t)(g),
      (__attribute__((address_space(3))) void*)(uint32_t)(uintptr_t)(lds),
      16, 0, 0);
}

// =====================================================================
// GEMM:  C = A[M,K] @ Bt[N,K]^T  +bias.  BK=32 everywhere (R11/R15:
// smaller per-barrier DMA drain + 4 blocks/CU beats bigger K-tiles).
// LDS double-buffered, async prefetch, one __syncthreads/iter, XOR
// swizzle (0 bank conflicts, verified R6).
// BM=128: 32 KB LDS. BM=64: 24 KB LDS. Both __launch_bounds__(256,4).
// EPI 1: bf16 = acc+bias+f32resid      2: bf16 = relu(acc+bias)
// EPI 3: QKV: col<512 Q*C2 row-major; col<1024 K row-major;
//        col>=1024 V -> aux = Vt[(b*8+h)*64+dk][s] transposed (8B stores)
// EPI 4: bf16 = acc+bias+bf16resid
// =====================================================================
template <int BM, int EPI>
__global__ __launch_bounds__(256, 4) void gemm_bt(
    const bf16* __restrict__ A, const bf16* __restrict__ Bt,
    const float* __restrict__ bias, const float* __restrict__ resid,
    const bf16* __restrict__ residb, bf16* __restrict__ aux,
    void* __restrict__ Cout, int M, int N, int K) {
  constexpr int BN = 128, BK = 32;
  constexpr int MI = BM / 32;          // m-frags per wave
  constexpr int AISS = (BM / 4) / 16;  // A issues per wave (16 rows/issue)
  __shared__ alignas(16) bf16 sA[2][BM * BK];
  __shared__ alignas(16) bf16 sB[2][BN * BK];
  const int tid = threadIdx.x;
  const int lane = tid & 63;
  const int wv = tid >> 6;
  const int n0 = blockIdx.x * BN;
  const int m0 = blockIdx.y * BM;

  const int srow = lane >> 2;                      // 16 rows per 64B issue
  const int sch = ((lane & 3) ^ (srow & 3)) * 8;   // swizzled k-elem offset
  const bf16* gA = A + (size_t)(m0 + wv * (BM / 4) + srow) * K + sch;
  const bf16* gB = Bt + (size_t)(n0 + wv * 32 + srow) * K + sch;

  const int wm = (wv >> 1) * (BM / 2);
  const int wn = (wv & 1) * 64;
  const int fr = lane & 15;
  const int fq = lane >> 4;
  const int fc = (fq ^ (fr & 3)) * 8;  // swizzled fragment chunk

  auto stage = [&](int buf, int k0) {
#pragma unroll
    for (int j = 0; j < AISS; ++j)
      load_lds16(sA[buf] + (wv * (BM / 4) + j * 16) * BK, gA + (size_t)(j * 16) * K + k0);
#pragma unroll
    for (int j = 0; j < 2; ++j)
      load_lds16(sB[buf] + (wv * 32 + j * 16) * BK, gB + (size_t)(j * 16) * K + k0);
  };

  f32x4 acc[MI][4] = {};

  stage(0, 0);
  __syncthreads();  // barrier's vmcnt(0) drain completes tile 0

  const int niter = K / BK;
  for (int it = 0; it < niter; ++it) {
    const int cur = it & 1;
    if (it + 1 < niter) stage(cur ^ 1, (it + 1) * BK);
    bf16x8 af[MI], bfr[4];
#pragma unroll
    for (int i = 0; i < MI; ++i)
      af[i] = *(const bf16x8*)(sA[cur] + (wm + i * 16 + fr) * BK + fc);
#pragma unroll
    for (int j = 0; j < 4; ++j)
      bfr[j] = *(const bf16x8*)(sB[cur] + (wn + j * 16 + fr) * BK + fc);
#pragma unroll
    for (int i = 0; i < MI; ++i)
#pragma unroll
      for (int j = 0; j < 4; ++j)
        acc[i][j] = __builtin_amdgcn_mfma_f32_16x16x32_bf16(af[i], bfr[j], acc[i][j], 0, 0, 0);
    __syncthreads();  // readers done with cur + prefetch DMA drained
  }

#pragma unroll
  for (int i = 0; i < MI; ++i) {
#pragma unroll
    for (int j = 0; j < 4; ++j) {
      const int col = n0 + wn + j * 16 + fr;
      const float bv = bias[col];
      if (EPI == 3 && col >= 1024) {
        const int row0 = m0 + wm + i * 16 + fq * 4;
        const int hh = (col - 1024) >> 6, dk = (col - 1024) & 63;
        const int bb = row0 >> 11, s0 = row0 & 2047;
        bf16 pv[4];
#pragma unroll
        for (int r = 0; r < 4; ++r) pv[r] = (bf16)(acc[i][j][r] + bv);
        *(uint2*)(aux + (size_t)((bb * 8 + hh) * 64 + dk) * 2048 + s0) = *(const uint2*)pv;
      } else {
#pragma unroll
        for (int r = 0; r < 4; ++r) {
          const int row = m0 + wm + i * 16 + fq * 4 + r;
          const size_t idx = (size_t)row * N + col;
          float v = acc[i][j][r] + bv;
          if (EPI == 1) {
            ((bf16*)Cout)[idx] = (bf16)(v + resid[idx]);
          } else if (EPI == 2) {
            ((bf16*)Cout)[idx] = (bf16)(v > 0.f ? v : 0.f);
          } else if (EPI == 3) {
            ((bf16*)Cout)[idx] = (bf16)(col < 512 ? v * C2f : v);
          } else {
            ((bf16*)Cout)[idx] = (bf16)(v + (float)residb[idx]);
          }
        }
      }
    }
  }
}

// =====================================================================
// Flash attention (R10 version verbatim — best measured: 52.0us).
// 4-wave blocks, 128 q-rows, 64-row K/V tiles double-buffered via
// global_load_lds, one __syncthreads/iter, max-free online softmax
// (scale folded into Q by QKV epilogue), XOR-swizzled LDS.
// =====================================================================
__global__ __launch_bounds__(256, 2) void flash_attn(
    const bf16* __restrict__ qkv, const bf16* __restrict__ Vt,
    bf16* __restrict__ ctx) {
  const int bid = blockIdx.x;
  const int qt = bid & 15;
  const int h = (bid >> 4) & 7;
  const int b = bid >> 7;
  const int q0 = qt * 128;
  const int tid = threadIdx.x, lane = tid & 63, wv = tid >> 6;
  const int fr = lane & 15, fq = lane >> 4;
  const int xsw = fr & 7;

  __shared__ alignas(16) bf16 sK[2][64 * 64];
  __shared__ alignas(16) bf16 sV[2][64 * 64];
  __shared__ alignas(16) bf16 sP[128 * 64];  // Q at start, then P (wave-private)

  const int srow = lane >> 3;                // 0..7 within 8-row issue
  const int scol = ((lane & 7) ^ srow) * 8;  // swizzled chunk (elements)

  const bf16* gQ = qkv + (size_t)(b * Sz + q0 + wv * 32 + srow) * 1536 + h * 64 + scol;
  const bf16* gK = qkv + (size_t)(b * Sz + wv * 16 + srow) * 1536 + 512 + h * 64 + scol;
  const bf16* gV = Vt + (size_t)((b * 8 + h) * 64 + wv * 16 + srow) * Sz + scol;

  // stage Q (wave-private 32 rows) and K/V tile 0
#pragma unroll
  for (int i = 0; i < 4; ++i)
    load_lds16(sP + (wv * 32 + i * 8) * 64, gQ + (size_t)(i * 8) * 1536);
  load_lds16(sK[0] + (wv * 16 + 0) * 64, gK);
  load_lds16(sK[0] + (wv * 16 + 8) * 64, gK + (size_t)8 * 1536);
  load_lds16(sV[0] + (wv * 16 + 0) * 64, gV);
  load_lds16(sV[0] + (wv * 16 + 8) * 64, gV + (size_t)8 * Sz);
  asm volatile("s_waitcnt vmcnt(0)" ::: "memory");  // own DMA (Q rows) visible
  __syncthreads();                                  // all waves' K/V tile 0 visible

  const int colc0 = (fq ^ xsw) * 8;
  const int colc1 = ((fq + 4) ^ xsw) * 8;
  int pcol[4], qsrc[4];
#pragma unroll
  for (int j = 0; j < 4; ++j)
    pcol[j] = (((fq + 4 * j) >> 1) ^ xsw) * 8 + (fq & 1) * 4;
#pragma unroll
  for (int r = 0; r < 4; ++r) qsrc[r] = (fq * 4 + r) | (lane & 48);

  // Q fragments -> registers (wave-private rows of sP)
  bf16x8 qb[2][2];
#pragma unroll
  for (int s = 0; s < 2; ++s) {
    qb[s][0] = *(const bf16x8*)(sP + (wv * 32 + s * 16 + fr) * 64 + colc0);
    qb[s][1] = *(const bf16x8*)(sP + (wv * 32 + s * 16 + fr) * 64 + colc1);
  }
  asm volatile("s_waitcnt lgkmcnt(0)" ::: "memory");

  float l_part[2] = {0.f, 0.f};
  f32x4 acc_o[2][4] = {};

  for (int it = 0; it < 32; ++it) {
    const int cur = it & 1;
    if (it + 1 < 32) {  // prefetch next K/V tile
      const int nxt = cur ^ 1;
      const size_t t1 = (size_t)(it + 1) * 64;
      load_lds16(sK[nxt] + (wv * 16 + 0) * 64, gK + t1 * 1536);
      load_lds16(sK[nxt] + (wv * 16 + 8) * 64, gK + (t1 + 8) * 1536);
      load_lds16(sV[nxt] + (wv * 16 + 0) * 64, gV + t1);
      load_lds16(sV[nxt] + (wv * 16 + 8) * 64, gV + (size_t)8 * Sz + t1);
    }

    // S^T = K Q^T : lane holds q=fr, t=fq*4+r+16j, per strip
    bf16x8 kf[2][4];
#pragma unroll
    for (int j = 0; j < 4; ++j) {
      kf[0][j] = *(const bf16x8*)(sK[cur] + (j * 16 + fr) * 64 + colc0);
      kf[1][j] = *(const bf16x8*)(sK[cur] + (j * 16 + fr) * 64 + colc1);
    }
    f32x4 sc[2][4] = {};
#pragma unroll
    for (int s = 0; s < 2; ++s)
#pragma unroll
      for (int kk = 0; kk < 2; ++kk)
#pragma unroll
        for (int j = 0; j < 4; ++j)
          sc[s][j] = __builtin_amdgcn_mfma_f32_16x16x32_bf16(kf[kk][j], qb[s][kk], sc[s][j], 0, 0, 0);

    // max-free softmax: e = exp2(sc), lane-local l accumulation
#pragma unroll
    for (int s = 0; s < 2; ++s) {
      float rs = 0.f;
#pragma unroll
      for (int j = 0; j < 4; ++j) {
        float e0 = __builtin_amdgcn_exp2f(sc[s][j][0]);
        float e1 = __builtin_amdgcn_exp2f(sc[s][j][1]);
        float e2 = __builtin_amdgcn_exp2f(sc[s][j][2]);
        float e3 = __builtin_amdgcn_exp2f(sc[s][j][3]);
        rs += (e0 + e1) + (e2 + e3);
        bf16 pt[4] = {(bf16)e0, (bf16)e1, (bf16)e2, (bf16)e3};
        *(uint2*)(sP + (wv * 32 + s * 16 + fr) * 64 + pcol[j]) = *(const uint2*)pt;
      }
      l_part[s] += rs;
    }
    asm volatile("s_waitcnt lgkmcnt(0)" ::: "memory");  // own sP writes visible

    // O += P V  (V frags shared across strips)
    bf16x8 vf[2][4];
#pragma unroll
    for (int j = 0; j < 4; ++j) {
      vf[0][j] = *(const bf16x8*)(sV[cur] + (j * 16 + fr) * 64 + colc0);
      vf[1][j] = *(const bf16x8*)(sV[cur] + (j * 16 + fr) * 64 + colc1);
    }
#pragma unroll
    for (int s = 0; s < 2; ++s)
#pragma unroll
      for (int kk = 0; kk < 2; ++kk) {
        bf16x8 ap = *(const bf16x8*)(sP + (wv * 32 + s * 16 + fr) * 64 + (kk ? colc1 : colc0));
#pragma unroll
        for (int j = 0; j < 4; ++j)
          acc_o[s][j] = __builtin_amdgcn_mfma_f32_16x16x32_bf16(ap, vf[kk][j], acc_o[s][j], 0, 0, 0);
      }
    __syncthreads();  // compute-reads done + prefetch DMA drained
  }

#pragma unroll
  for (int s = 0; s < 2; ++s) {
    float l = l_part[s];
    l += __shfl_xor(l, 16, 64);
    l += __shfl_xor(l, 32, 64);
    float rl[4];
#pragma unroll
    for (int r = 0; r < 4; ++r) rl[r] = 1.0f / __shfl(l, qsrc[r], 64);
#pragma unroll
    for (int j = 0; j < 4; ++j)
#pragma unroll
      for (int r = 0; r < 4; ++r) {
        const int row = b * Sz + q0 + wv * 32 + s * 16 + fq * 4 + r;
        const int col = h * 64 + j * 16 + fr;
        ctx[(size_t)row * Dz + col] = (bf16)(acc_o[s][j][r] * rl[r]);
      }
  }
}

// =====================================================================
// LayerNorm: one wave per row of 512. bf16 input; fp32 or bf16 output.
// =====================================================================
template <int OUT_F32>
__global__ __launch_bounds__(256) void layer_norm_k(
    const bf16* __restrict__ y, const float* __restrict__ g,
    const float* __restrict__ be, void* __restrict__ out) {
  const int row = blockIdx.x * 4 + (threadIdx.x >> 6);
  const int lane = threadIdx.x & 63;
  const int col = lane * 8;
  bf16x8 hv = *(const bf16x8*)(y + (size_t)row * Dz + col);
  float v[8];
  float s = 0.f, ss = 0.f;
#pragma unroll
  for (int i = 0; i < 8; ++i) {
    v[i] = (float)hv[i];
    s += v[i];
    ss += v[i] * v[i];
  }
#pragma unroll
  for (int o = 1; o < 64; o <<= 1) {
    s += __shfl_xor(s, o, 64);
    ss += __shfl_xor(ss, o, 64);
  }
  const float mu = s * (1.0f / Dz);
  const float rstd = rsqrtf(ss * (1.0f / Dz) - mu * mu + EPSf);
  const float4* g4 = (const float4*)(g + col);
  const float4* b4 = (const float4*)(be + col);
  float4 ga = g4[0], gb = g4[1], ba = b4[0], bb = b4[1];
  float o8[8];
  o8[0] = (v[0] - mu) * rstd * ga.x + ba.x;
  o8[1] = (v[1] - mu) * rstd * ga.y + ba.y;
  o8[2] = (v[2] - mu) * rstd * ga.z + ba.z;
  o8[3] = (v[3] - mu) * rstd * ga.w + ba.w;
  o8[4] = (v[4] - mu) * rstd * gb.x + bb.x;
  o8[5] = (v[5] - mu) * rstd * gb.y + bb.y;
  o8[6] = (v[6] - mu) * rstd * gb.z + bb.z;
  o8[7] = (v[7] - mu) * rstd * gb.w + bb.w;
  if (OUT_F32) {
    float4* of = (float4*)((float*)out + (size_t)row * Dz + col);
    of[0] = make_float4(o8[0], o8[1], o8[2], o8[3]);
    of[1] = make_float4(o8[4], o8[5], o8[6], o8[7]);
  } else {
    bf16 ob[8];
#pragma unroll
    for (int i = 0; i < 8; ++i) ob[i] = (bf16)o8[i];
    *(uint4*)((bf16*)out + (size_t)row * Dz + col) = *(const uint4*)ob;
  }
}

// =====================================================================
// Fused prep: all 6 weight transposes (fp32[K,N] -> bf16[N,K], 64x64
// tiles), bias concat, x -> bf16 cast. One launch.
// =====================================================================
__global__ __launch_bounds__(256) void prep_all(
    const float* __restrict__ Wq, const float* __restrict__ Wk,
    const float* __restrict__ Wv, const float* __restrict__ Wo,
    const float* __restrict__ W1, const float* __restrict__ W2,
    const float* __restrict__ bq, const float* __restrict__ bk,
    const float* __restrict__ bv, const float* __restrict__ x,
    bf16* __restrict__ WqkvT, bf16* __restrict__ WoT,
    bf16* __restrict__ W1T, bf16* __restrict__ W2T,
    float* __restrict__ bqkv, bf16* __restrict__ xb) {
  __shared__ float tile[64][65];
  const int blk = blockIdx.x;
  const int t = threadIdx.x;
  if (blk < 768) {
    const float* W;
    bf16* Wt;
    int K, N, local;
    if (blk < 64)       { W = Wq; Wt = WqkvT;                       K = 512;  N = 512;  local = blk; }
    else if (blk < 128) { W = Wk; Wt = WqkvT + (size_t)512 * 512;   K = 512;  N = 512;  local = blk - 64; }
    else if (blk < 192) { W = Wv; Wt = WqkvT + (size_t)1024 * 512;  K = 512;  N = 512;  local = blk - 128; }
    else if (blk < 256) { W = Wo; Wt = WoT;                         K = 512;  N = 512;  local = blk - 192; }
    else if (blk < 512) { W = W1; Wt = W1T;                         K = 512;  N = 2048; local = blk - 256; }
    else                { W = W2; Wt = W2T;                         K = 2048; N = 512;  local = blk - 512; }
    const int kt = K / 64;
    const int k0 = (local % kt) * 64, n0 = (local / kt) * 64;
    const int r = t >> 2, c = (t & 3) * 16;
    const float* src = W + (size_t)(k0 + r) * N + n0 + c;
#pragma unroll
    for (int i = 0; i < 4; ++i) {
      float4 v = ((const float4*)src)[i];
      tile[r][c + i * 4 + 0] = v.x;
      tile[r][c + i * 4 + 1] = v.y;
      tile[r][c + i * 4 + 2] = v.z;
      tile[r][c + i * 4 + 3] = v.w;
    }
    __syncthreads();
    union { bf16 hh[16]; uint4 u[2]; } pk;
#pragma unroll
    for (int i = 0; i < 16; ++i) pk.hh[i] = (bf16)tile[c + i][r];
    uint4* dst = (uint4*)(Wt + (size_t)(n0 + r) * K + k0 + c);
    dst[0] = pk.u[0];
    dst[1] = pk.u[1];
  } else if (blk == 768) {
    for (int i = t; i < 1536; i += 256)
      bqkv[i] = i < 512 ? bq[i] : (i < 1024 ? bk[i - 512] : bv[i - 1024]);
  } else {
    const int local = blk - 769;  // 0..1023, each handles 1024 float4s
#pragma unroll
    for (int k = 0; k < 4; ++k) {
      const int i = local * 1024 + k * 256 + t;
      float4 v = ((const float4*)x)[i];
      bf16 tv[4] = {(bf16)v.x, (bf16)v.y, (bf16)v.z, (bf16)v.w};
      ((uint2*)xb)[i] = *(const uint2*)tv;
    }
  }
}

// =====================================================================
extern "C" void kernel_launch(void* const* d_in, const int* in_sizes, int n_in,
                              void* d_out, int out_size, void* d_ws, size_t ws_size,
                              hipStream_t stream) {
  const float* x   = (const float*)d_in[0];
  const float* Wq  = (const float*)d_in[1];
  const float* bq  = (const float*)d_in[2];
  const float* Wk  = (const float*)d_in[3];
  const float* bk  = (const float*)d_in[4];
  const float* Wv  = (const float*)d_in[5];
  const float* bvp = (const float*)d_in[6];
  const float* Wo  = (const float*)d_in[7];
  const float* bo  = (const float*)d_in[8];
  const float* W1  = (const float*)d_in[9];
  const float* b1  = (const float*)d_in[10];
  const float* W2  = (const float*)d_in[11];
  const float* b2  = (const float*)d_in[12];
  const float* g1  = (const float*)d_in[13];
  const float* be1 = (const float*)d_in[14];
  const float* g2  = (const float*)d_in[15];
  const float* be2 = (const float*)d_in[16];

  char* ws = (char*)d_ws;
  size_t off = 0;
  auto alloc = [&](size_t bytes) -> void* {
    void* p = ws + off;
    off += (bytes + 255) & ~(size_t)255;
    return p;
  };
  bf16*  WqkvT = (bf16*)alloc((size_t)1536 * 512 * 2);
  float* bqkv  = (float*)alloc(1536 * 4);
  bf16*  WoT   = (bf16*)alloc((size_t)512 * 512 * 2);
  bf16*  W1T   = (bf16*)alloc((size_t)2048 * 512 * 2);
  bf16*  W2T   = (bf16*)alloc((size_t)512 * 2048 * 2);
  bf16*  xb    = (bf16*)alloc((size_t)ROWSz * 512 * 2);
  bf16*  qkv   = (bf16*)alloc((size_t)ROWSz * 1536 * 2);    // 24 MB (Q,K rows)
  bf16*  Vt    = (bf16*)alloc((size_t)32 * 64 * 2048 * 2);  // 8 MB, written by QKV epilogue
  bf16*  ctx   = (bf16*)alloc((size_t)ROWSz * 512 * 2);
  bf16*  y1    = (bf16*)alloc((size_t)ROWSz * 512 * 2);     // Wo+resid out (bf16)
  bf16*  x1b   = (bf16*)alloc((size_t)ROWSz * 512 * 2);     // LN1 out
  bf16*  hbuf  = qkv;  // 32 MB alias over qkv+Vt (dead after attention+Wo)
  bf16*  y2    = y1;   // dead after LN1

  // fused prep (weights, bias concat, x cast)
  prep_all<<<dim3(1793), 256, 0, stream>>>(Wq, Wk, Wv, Wo, W1, W2, bq, bk, bvp, x,
                                           WqkvT, WoT, W1T, W2T, bqkv, xb);

  // QKV projection (fused N=1536; Q cols pre-scaled by C2; V cols -> Vt transposed)
  gemm_bt<128, 3><<<dim3(12, 64), 256, 0, stream>>>(xb, WqkvT, bqkv, nullptr, nullptr, Vt, qkv, ROWSz, 1536, 512);
  // attention (4-wave blocks, 128 q each)
  flash_attn<<<dim3(512), 256, 0, stream>>>(qkv, Vt, ctx);
  // Wo + bias + residual(xb bf16) -> y1 bf16
  gemm_bt<64, 4><<<dim3(4, 128), 256, 0, stream>>>(ctx, WoT, bo, nullptr, xb, nullptr, y1, ROWSz, 512, 512);
  layer_norm_k<0><<<dim3(2048), 256, 0, stream>>>(y1, g1, be1, x1b);
  // FFN
  gemm_bt<128, 2><<<dim3(16, 64), 256, 0, stream>>>(x1b, W1T, b1, nullptr, nullptr, nullptr, hbuf, ROWSz, 2048, 512);
  gemm_bt<64, 4><<<dim3(4, 128), 256, 0, stream>>>(hbuf, W2T, b2, nullptr, x1b, nullptr, y2, ROWSz, 512, 2048);
  layer_norm_k<1><<<dim3(2048), 256, 0, stream>>>(y2, g2, be2, d_out);
}

// Round 16
// 242.977 us; speedup vs baseline: 1.0277x; 1.0277x over previous
//
#include <hip/hip_runtime.h>
#include <hip/hip_bf16.h>
#include <stdint.h>

typedef __bf16 bf16;
typedef __attribute__((ext_vector_type(8))) __bf16 bf16x8;
typedef __attribute__((ext_vector_type(4))) float f32x4;

#define DEVI __device__ __forceinline__

constexpr int Bz = 4, Sz = 2048, Dz = 512, Hz = 8, DKz = 64, DFFz = 2048;
constexpr int ROWSz = Bz * Sz;  // 8192
constexpr float EPSf = 1e-5f;
constexpr float C2f = 0.125f * 1.44269504088896f;  // 1/sqrt(DK) * log2(e)

// ---- async global->LDS, 16B per lane. LDS dest is wave-uniform base + lane*16.
DEVI void load_lds16(void* lds, const void* g) {
  __builtin_amdgcn_global_load_lds(
      (const __attribute__((address_space(1))) void*)(uintptr_t)(g),
      (__attribute__((address_space(3))) void*)(uint32_t)(uintptr_t)(lds),
      16, 0, 0);
}

// =====================================================================
// GEMM (best measured mix, R11/R14):  C = A[M,K] @ Bt[N,K]^T  +bias.
// LDS double-buffered, async prefetch, one __syncthreads/iter, XOR
// swizzle (0 bank conflicts, verified R6).
// BM=128/BK=32: 32 KB LDS, 4 blocks/CU (R11: smaller per-barrier drain
//   + more independent DMA streams wins at this shape).
// BM=64 /BK=64: 48 KB LDS, 3 blocks/CU (R15 falsified BK=32 here: thin
//   iterations make per-barrier fixed cost dominant).
// EPI 1: bf16 = acc+bias+f32resid      2: bf16 = relu(acc+bias)
// EPI 3: QKV: col<512 Q*C2 row-major; col<1024 K row-major;
//        col>=1024 V -> aux = Vt[(b*8+h)*64+dk][s] transposed (8B stores)
// EPI 4: bf16 = acc+bias+bf16resid
// =====================================================================
template <int BM, int BK, int EPI>
__global__ __launch_bounds__(256, BM == 128 ? 4 : 3) void gemm_bt(
    const bf16* __restrict__ A, const bf16* __restrict__ Bt,
    const float* __restrict__ bias, const float* __restrict__ resid,
    const bf16* __restrict__ residb, bf16* __restrict__ aux,
    void* __restrict__ Cout, int M, int N, int K) {
  constexpr int BN = 128;
  constexpr int MI = BM / 32;          // m-frags per wave
  constexpr int RPI = 512 / BK;        // rows per 16B-issue (16 @BK32, 8 @BK64)
  constexpr int AISS = (BM / 4) / RPI; // A issues per wave
  constexpr int BISS = 32 / RPI;       // B issues per wave
  __shared__ alignas(16) bf16 sA[2][BM * BK];
  __shared__ alignas(16) bf16 sB[2][BN * BK];
  const int tid = threadIdx.x;
  const int lane = tid & 63;
  const int wv = tid >> 6;
  const int n0 = blockIdx.x * BN;
  const int m0 = blockIdx.y * BM;

  const int srow = (BK == 32) ? (lane >> 2) : (lane >> 3);
  const int sch = (BK == 32) ? (((lane & 3) ^ (srow & 3)) * 8)
                             : (((lane & 7) ^ (srow & 7)) * 8);
  const bf16* gA = A + (size_t)(m0 + wv * (BM / 4) + srow) * K + sch;
  const bf16* gB = Bt + (size_t)(n0 + wv * 32 + srow) * K + sch;

  const int wm = (wv >> 1) * (BM / 2);
  const int wn = (wv & 1) * 64;
  const int fr = lane & 15;
  const int fq = lane >> 4;

  auto stage = [&](int buf, int k0) {
#pragma unroll
    for (int j = 0; j < AISS; ++j)
      load_lds16(sA[buf] + (wv * (BM / 4) + j * RPI) * BK, gA + (size_t)(j * RPI) * K + k0);
#pragma unroll
    for (int j = 0; j < BISS; ++j)
      load_lds16(sB[buf] + (wv * 32 + j * RPI) * BK, gB + (size_t)(j * RPI) * K + k0);
  };

  f32x4 acc[MI][4] = {};

  stage(0, 0);
  __syncthreads();  // barrier's vmcnt(0) drain completes tile 0

  const int niter = K / BK;
  for (int it = 0; it < niter; ++it) {
    const int cur = it & 1;
    if (it + 1 < niter) stage(cur ^ 1, (it + 1) * BK);
#pragma unroll
    for (int kk = 0; kk < BK / 32; ++kk) {
      const int fc = (BK == 32) ? ((fq ^ (fr & 3)) * 8)
                                : (((4 * kk + fq) ^ (fr & 7)) * 8);
      bf16x8 af[MI], bfr[4];
#pragma unroll
      for (int i = 0; i < MI; ++i)
        af[i] = *(const bf16x8*)(sA[cur] + (wm + i * 16 + fr) * BK + fc);
#pragma unroll
      for (int j = 0; j < 4; ++j)
        bfr[j] = *(const bf16x8*)(sB[cur] + (wn + j * 16 + fr) * BK + fc);
#pragma unroll
      for (int i = 0; i < MI; ++i)
#pragma unroll
        for (int j = 0; j < 4; ++j)
          acc[i][j] = __builtin_amdgcn_mfma_f32_16x16x32_bf16(af[i], bfr[j], acc[i][j], 0, 0, 0);
    }
    __syncthreads();  // readers done with cur + prefetch DMA drained
  }

#pragma unroll
  for (int i = 0; i < MI; ++i) {
#pragma unroll
    for (int j = 0; j < 4; ++j) {
      const int col = n0 + wn + j * 16 + fr;
      const float bv = bias[col];
      if (EPI == 3 && col >= 1024) {
        const int row0 = m0 + wm + i * 16 + fq * 4;
        const int hh = (col - 1024) >> 6, dk = (col - 1024) & 63;
        const int bb = row0 >> 11, s0 = row0 & 2047;
        bf16 pv[4];
#pragma unroll
        for (int r = 0; r < 4; ++r) pv[r] = (bf16)(acc[i][j][r] + bv);
        *(uint2*)(aux + (size_t)((bb * 8 + hh) * 64 + dk) * 2048 + s0) = *(const uint2*)pv;
      } else {
#pragma unroll
        for (int r = 0; r < 4; ++r) {
          const int row = m0 + wm + i * 16 + fq * 4 + r;
          const size_t idx = (size_t)row * N + col;
          float v = acc[i][j][r] + bv;
          if (EPI == 1) {
            ((bf16*)Cout)[idx] = (bf16)(v + resid[idx]);
          } else if (EPI == 2) {
            ((bf16*)Cout)[idx] = (bf16)(v > 0.f ? v : 0.f);
          } else if (EPI == 3) {
            ((bf16*)Cout)[idx] = (bf16)(col < 512 ? v * C2f : v);
          } else {
            ((bf16*)Cout)[idx] = (bf16)(v + (float)residb[idx]);
          }
        }
      }
    }
  }
}

// =====================================================================
// Flash attention (R10 version verbatim — best measured: ~51.7us).
// 4-wave blocks, 128 q-rows, 64-row K/V tiles double-buffered via
// global_load_lds, one __syncthreads/iter, max-free online softmax
// (scale folded into Q by QKV epilogue), XOR-swizzled LDS.
// =====================================================================
__global__ __launch_bounds__(256, 2) void flash_attn(
    const bf16* __restrict__ qkv, const bf16* __restrict__ Vt,
    bf16* __restrict__ ctx) {
  const int bid = blockIdx.x;
  const int qt = bid & 15;
  const int h = (bid >> 4) & 7;
  const int b = bid >> 7;
  const int q0 = qt * 128;
  const int tid = threadIdx.x, lane = tid & 63, wv = tid >> 6;
  const int fr = lane & 15, fq = lane >> 4;
  const int xsw = fr & 7;

  __shared__ alignas(16) bf16 sK[2][64 * 64];
  __shared__ alignas(16) bf16 sV[2][64 * 64];
  __shared__ alignas(16) bf16 sP[128 * 64];  // Q at start, then P (wave-private)

  const int srow = lane >> 3;                // 0..7 within 8-row issue
  const int scol = ((lane & 7) ^ srow) * 8;  // swizzled chunk (elements)

  const bf16* gQ = qkv + (size_t)(b * Sz + q0 + wv * 32 + srow) * 1536 + h * 64 + scol;
  const bf16* gK = qkv + (size_t)(b * Sz + wv * 16 + srow) * 1536 + 512 + h * 64 + scol;
  const bf16* gV = Vt + (size_t)((b * 8 + h) * 64 + wv * 16 + srow) * Sz + scol;

  // stage Q (wave-private 32 rows) and K/V tile 0
#pragma unroll
  for (int i = 0; i < 4; ++i)
    load_lds16(sP + (wv * 32 + i * 8) * 64, gQ + (size_t)(i * 8) * 1536);
  load_lds16(sK[0] + (wv * 16 + 0) * 64, gK);
  load_lds16(sK[0] + (wv * 16 + 8) * 64, gK + (size_t)8 * 1536);
  load_lds16(sV[0] + (wv * 16 + 0) * 64, gV);
  load_lds16(sV[0] + (wv * 16 + 8) * 64, gV + (size_t)8 * Sz);
  asm volatile("s_waitcnt vmcnt(0)" ::: "memory");  // own DMA (Q rows) visible
  __syncthreads();                                  // all waves' K/V tile 0 visible

  const int colc0 = (fq ^ xsw) * 8;
  const int colc1 = ((fq + 4) ^ xsw) * 8;
  int pcol[4], qsrc[4];
#pragma unroll
  for (int j = 0; j < 4; ++j)
    pcol[j] = (((fq + 4 * j) >> 1) ^ xsw) * 8 + (fq & 1) * 4;
#pragma unroll
  for (int r = 0; r < 4; ++r) qsrc[r] = (fq * 4 + r) | (lane & 48);

  // Q fragments -> registers (wave-private rows of sP)
  bf16x8 qb[2][2];
#pragma unroll
  for (int s = 0; s < 2; ++s) {
    qb[s][0] = *(const bf16x8*)(sP + (wv * 32 + s * 16 + fr) * 64 + colc0);
    qb[s][1] = *(const bf16x8*)(sP + (wv * 32 + s * 16 + fr) * 64 + colc1);
  }
  asm volatile("s_waitcnt lgkmcnt(0)" ::: "memory");

  float l_part[2] = {0.f, 0.f};
  f32x4 acc_o[2][4] = {};

  for (int it = 0; it < 32; ++it) {
    const int cur = it & 1;
    if (it + 1 < 32) {  // prefetch next K/V tile
      const int nxt = cur ^ 1;
      const size_t t1 = (size_t)(it + 1) * 64;
      load_lds16(sK[nxt] + (wv * 16 + 0) * 64, gK + t1 * 1536);
      load_lds16(sK[nxt] + (wv * 16 + 8) * 64, gK + (t1 + 8) * 1536);
      load_lds16(sV[nxt] + (wv * 16 + 0) * 64, gV + t1);
      load_lds16(sV[nxt] + (wv * 16 + 8) * 64, gV + (size_t)8 * Sz + t1);
    }

    // S^T = K Q^T : lane holds q=fr, t=fq*4+r+16j, per strip
    bf16x8 kf[2][4];
#pragma unroll
    for (int j = 0; j < 4; ++j) {
      kf[0][j] = *(const bf16x8*)(sK[cur] + (j * 16 + fr) * 64 + colc0);
      kf[1][j] = *(const bf16x8*)(sK[cur] + (j * 16 + fr) * 64 + colc1);
    }
    f32x4 sc[2][4] = {};
#pragma unroll
    for (int s = 0; s < 2; ++s)
#pragma unroll
      for (int kk = 0; kk < 2; ++kk)
#pragma unroll
        for (int j = 0; j < 4; ++j)
          sc[s][j] = __builtin_amdgcn_mfma_f32_16x16x32_bf16(kf[kk][j], qb[s][kk], sc[s][j], 0, 0, 0);

    // max-free softmax: e = exp2(sc), lane-local l accumulation
#pragma unroll
    for (int s = 0; s < 2; ++s) {
      float rs = 0.f;
#pragma unroll
      for (int j = 0; j < 4; ++j) {
        float e0 = __builtin_amdgcn_exp2f(sc[s][j][0]);
        float e1 = __builtin_amdgcn_exp2f(sc[s][j][1]);
        float e2 = __builtin_amdgcn_exp2f(sc[s][j][2]);
        float e3 = __builtin_amdgcn_exp2f(sc[s][j][3]);
        rs += (e0 + e1) + (e2 + e3);
        bf16 pt[4] = {(bf16)e0, (bf16)e1, (bf16)e2, (bf16)e3};
        *(uint2*)(sP + (wv * 32 + s * 16 + fr) * 64 + pcol[j]) = *(const uint2*)pt;
      }
      l_part[s] += rs;
    }
    asm volatile("s_waitcnt lgkmcnt(0)" ::: "memory");  // own sP writes visible

    // O += P V  (V frags shared across strips)
    bf16x8 vf[2][4];
#pragma unroll
    for (int j = 0; j < 4; ++j) {
      vf[0][j] = *(const bf16x8*)(sV[cur] + (j * 16 + fr) * 64 + colc0);
      vf[1][j] = *(const bf16x8*)(sV[cur] + (j * 16 + fr) * 64 + colc1);
    }
#pragma unroll
    for (int s = 0; s < 2; ++s)
#pragma unroll
      for (int kk = 0; kk < 2; ++kk) {
        bf16x8 ap = *(const bf16x8*)(sP + (wv * 32 + s * 16 + fr) * 64 + (kk ? colc1 : colc0));
#pragma unroll
        for (int j = 0; j < 4; ++j)
          acc_o[s][j] = __builtin_amdgcn_mfma_f32_16x16x32_bf16(ap, vf[kk][j], acc_o[s][j], 0, 0, 0);
      }
    __syncthreads();  // compute-reads done + prefetch DMA drained
  }

#pragma unroll
  for (int s = 0; s < 2; ++s) {
    float l = l_part[s];
    l += __shfl_xor(l, 16, 64);
    l += __shfl_xor(l, 32, 64);
    float rl[4];
#pragma unroll
    for (int r = 0; r < 4; ++r) rl[r] = 1.0f / __shfl(l, qsrc[r], 64);
#pragma unroll
    for (int j = 0; j < 4; ++j)
#pragma unroll
      for (int r = 0; r < 4; ++r) {
        const int row = b * Sz + q0 + wv * 32 + s * 16 + fq * 4 + r;
        const int col = h * 64 + j * 16 + fr;
        ctx[(size_t)row * Dz + col] = (bf16)(acc_o[s][j][r] * rl[r]);
      }
  }
}

// =====================================================================
// LayerNorm: one wave per row of 512. bf16 input; fp32 or bf16 output.
// =====================================================================
template <int OUT_F32>
__global__ __launch_bounds__(256) void layer_norm_k(
    const bf16* __restrict__ y, const float* __restrict__ g,
    const float* __restrict__ be, void* __restrict__ out) {
  const int row = blockIdx.x * 4 + (threadIdx.x >> 6);
  const int lane = threadIdx.x & 63;
  const int col = lane * 8;
  bf16x8 hv = *(const bf16x8*)(y + (size_t)row * Dz + col);
  float v[8];
  float s = 0.f, ss = 0.f;
#pragma unroll
  for (int i = 0; i < 8; ++i) {
    v[i] = (float)hv[i];
    s += v[i];
    ss += v[i] * v[i];
  }
#pragma unroll
  for (int o = 1; o < 64; o <<= 1) {
    s += __shfl_xor(s, o, 64);
    ss += __shfl_xor(ss, o, 64);
  }
  const float mu = s * (1.0f / Dz);
  const float rstd = rsqrtf(ss * (1.0f / Dz) - mu * mu + EPSf);
  const float4* g4 = (const float4*)(g + col);
  const float4* b4 = (const float4*)(be + col);
  float4 ga = g4[0], gb = g4[1], ba = b4[0], bb = b4[1];
  float o8[8];
  o8[0] = (v[0] - mu) * rstd * ga.x + ba.x;
  o8[1] = (v[1] - mu) * rstd * ga.y + ba.y;
  o8[2] = (v[2] - mu) * rstd * ga.z + ba.z;
  o8[3] = (v[3] - mu) * rstd * ga.w + ba.w;
  o8[4] = (v[4] - mu) * rstd * gb.x + bb.x;
  o8[5] = (v[5] - mu) * rstd * gb.y + bb.y;
  o8[6] = (v[6] - mu) * rstd * gb.z + bb.z;
  o8[7] = (v[7] - mu) * rstd * gb.w + bb.w;
  if (OUT_F32) {
    float4* of = (float4*)((float*)out + (size_t)row * Dz + col);
    of[0] = make_float4(o8[0], o8[1], o8[2], o8[3]);
    of[1] = make_float4(o8[4], o8[5], o8[6], o8[7]);
  } else {
    bf16 ob[8];
#pragma unroll
    for (int i = 0; i < 8; ++i) ob[i] = (bf16)o8[i];
    *(uint4*)((bf16*)out + (size_t)row * Dz + col) = *(const uint4*)ob;
  }
}

// =====================================================================
// Fused prep: all 6 weight transposes (fp32[K,N] -> bf16[N,K], 64x64
// tiles), bias concat, x -> bf16 cast. One launch.
// =====================================================================
__global__ __launch_bounds__(256) void prep_all(
    const float* __restrict__ Wq, const float* __restrict__ Wk,
    const float* __restrict__ Wv, const float* __restrict__ Wo,
    const float* __restrict__ W1, const float* __restrict__ W2,
    const float* __restrict__ bq, const float* __restrict__ bk,
    const float* __restrict__ bv, const float* __restrict__ x,
    bf16* __restrict__ WqkvT, bf16* __restrict__ WoT,
    bf16* __restrict__ W1T, bf16* __restrict__ W2T,
    float* __restrict__ bqkv, bf16* __restrict__ xb) {
  __shared__ float tile[64][65];
  const int blk = blockIdx.x;
  const int t = threadIdx.x;
  if (blk < 768) {
    const float* W;
    bf16* Wt;
    int K, N, local;
    if (blk < 64)       { W = Wq; Wt = WqkvT;                       K = 512;  N = 512;  local = blk; }
    else if (blk < 128) { W = Wk; Wt = WqkvT + (size_t)512 * 512;   K = 512;  N = 512;  local = blk - 64; }
    else if (blk < 192) { W = Wv; Wt = WqkvT + (size_t)1024 * 512;  K = 512;  N = 512;  local = blk - 128; }
    else if (blk < 256) { W = Wo; Wt = WoT;                         K = 512;  N = 512;  local = blk - 192; }
    else if (blk < 512) { W = W1; Wt = W1T;                         K = 512;  N = 2048; local = blk - 256; }
    else                { W = W2; Wt = W2T;                         K = 2048; N = 512;  local = blk - 512; }
    const int kt = K / 64;
    const int k0 = (local % kt) * 64, n0 = (local / kt) * 64;
    const int r = t >> 2, c = (t & 3) * 16;
    const float* src = W + (size_t)(k0 + r) * N + n0 + c;
#pragma unroll
    for (int i = 0; i < 4; ++i) {
      float4 v = ((const float4*)src)[i];
      tile[r][c + i * 4 + 0] = v.x;
      tile[r][c + i * 4 + 1] = v.y;
      tile[r][c + i * 4 + 2] = v.z;
      tile[r][c + i * 4 + 3] = v.w;
    }
    __syncthreads();
    union { bf16 hh[16]; uint4 u[2]; } pk;
#pragma unroll
    for (int i = 0; i < 16; ++i) pk.hh[i] = (bf16)tile[c + i][r];
    uint4* dst = (uint4*)(Wt + (size_t)(n0 + r) * K + k0 + c);
    dst[0] = pk.u[0];
    dst[1] = pk.u[1];
  } else if (blk == 768) {
    for (int i = t; i < 1536; i += 256)
      bqkv[i] = i < 512 ? bq[i] : (i < 1024 ? bk[i - 512] : bv[i - 1024]);
  } else {
    const int local = blk - 769;  // 0..1023, each handles 1024 float4s
#pragma unroll
    for (int k = 0; k < 4; ++k) {
      const int i = local * 1024 + k * 256 + t;
      float4 v = ((const float4*)x)[i];
      bf16 tv[4] = {(bf16)v.x, (bf16)v.y, (bf16)v.z, (bf16)v.w};
      ((uint2*)xb)[i] = *(const uint2*)tv;
    }
  }
}

// =====================================================================
extern "C" void kernel_launch(void* const* d_in, const int* in_sizes, int n_in,
                              void* d_out, int out_size, void* d_ws, size_t ws_size,
                              hipStream_t stream) {
  const float* x   = (const float*)d_in[0];
  const float* Wq  = (const float*)d_in[1];
  const float* bq  = (const float*)d_in[2];
  const float* Wk  = (const float*)d_in[3];
  const float* bk  = (const float*)d_in[4];
  const float* Wv  = (const float*)d_in[5];
  const float* bvp = (const float*)d_in[6];
  const float* Wo  = (const float*)d_in[7];
  const float* bo  = (const float*)d_in[8];
  const float* W1  = (const float*)d_in[9];
  const float* b1  = (const float*)d_in[10];
  const float* W2  = (const float*)d_in[11];
  const float* b2  = (const float*)d_in[12];
  const float* g1  = (const float*)d_in[13];
  const float* be1 = (const float*)d_in[14];
  const float* g2  = (const float*)d_in[15];
  const float* be2 = (const float*)d_in[16];

  char* ws = (char*)d_ws;
  size_t off = 0;
  auto alloc = [&](size_t bytes) -> void* {
    void* p = ws + off;
    off += (bytes + 255) & ~(size_t)255;
    return p;
  };
  bf16*  WqkvT = (bf16*)alloc((size_t)1536 * 512 * 2);
  float* bqkv  = (float*)alloc(1536 * 4);
  bf16*  WoT   = (bf16*)alloc((size_t)512 * 512 * 2);
  bf16*  W1T   = (bf16*)alloc((size_t)2048 * 512 * 2);
  bf16*  W2T   = (bf16*)alloc((size_t)512 * 2048 * 2);
  bf16*  xb    = (bf16*)alloc((size_t)ROWSz * 512 * 2);
  bf16*  qkv   = (bf16*)alloc((size_t)ROWSz * 1536 * 2);    // 24 MB (Q,K rows)
  bf16*  Vt    = (bf16*)alloc((size_t)32 * 64 * 2048 * 2);  // 8 MB, written by QKV epilogue
  bf16*  ctx   = (bf16*)alloc((size_t)ROWSz * 512 * 2);
  bf16*  y1    = (bf16*)alloc((size_t)ROWSz * 512 * 2);     // Wo+resid out (bf16)
  bf16*  x1b   = (bf16*)alloc((size_t)ROWSz * 512 * 2);     // LN1 out
  bf16*  hbuf  = qkv;  // 32 MB alias over qkv+Vt (dead after attention+Wo)
  bf16*  y2    = y1;   // dead after LN1

  // fused prep (weights, bias concat, x cast)
  prep_all<<<dim3(1793), 256, 0, stream>>>(Wq, Wk, Wv, Wo, W1, W2, bq, bk, bvp, x,
                                           WqkvT, WoT, W1T, W2T, bqkv, xb);

  // QKV projection (fused N=1536; Q cols pre-scaled by C2; V cols -> Vt transposed)
  gemm_bt<128, 32, 3><<<dim3(12, 64), 256, 0, stream>>>(xb, WqkvT, bqkv, nullptr, nullptr, Vt, qkv, ROWSz, 1536, 512);
  // attention (4-wave blocks, 128 q each)
  flash_attn<<<dim3(512), 256, 0, stream>>>(qkv, Vt, ctx);
  // Wo + bias + residual(xb bf16) -> y1 bf16
  gemm_bt<64, 64, 4><<<dim3(4, 128), 256, 0, stream>>>(ctx, WoT, bo, nullptr, xb, nullptr, y1, ROWSz, 512, 512);
  layer_norm_k<0><<<dim3(2048), 256, 0, stream>>>(y1, g1, be1, x1b);
  // FFN
  gemm_bt<128, 32, 2><<<dim3(16, 64), 256, 0, stream>>>(x1b, W1T, b1, nullptr, nullptr, nullptr, hbuf, ROWSz, 2048, 512);
  gemm_bt<64, 64, 4><<<dim3(4, 128), 256, 0, stream>>>(hbuf, W2T, b2, nullptr, x1b, nullptr, y2, ROWSz, 512, 2048);
  layer_norm_k<1><<<dim3(2048), 256, 0, stream>>>(y2, g2, be2, d_out);
}